// Round 10
// baseline (111.119 us; speedup 1.0000x reference)
//
#include <hip/hip_runtime.h>
#include <math.h>

// ManifoldHyperConnectionFuse on MI355X — R9: 512-thread blocks, no spill.
// R8 post-mortem: VGPR=84 < the ~140 needed => w2r[16][6] lived in SCRATCH,
// and the in-loop asm pin forced a 96-float scratch reload per token:
// ~3.2 GB of L2 traffic per launch ~= the L2 ceiling at 89us. Fix: halve the
// per-thread weight footprint. 512 threads (8 waves = 8 k-eighths), each
// thread owns w2r[8][6] = 48 weights -> ~85 live VGPR, fits under the
// launch_bounds(512,4) cap of 128. Everything else structurally identical.
//
// Phase A: k = 128*wv + 64*e + 4*ksl + c (coalesced 256B segments),
//          DPP row16 reduce, Cpart[8][16][28]. 1 barrier.
// Reduce (8-way). 1 barrier. Scalar phase (lanes 0..15). 1 barrier.
// Phase C: wave = (n = wv&3, token-half = wv>>2), 8 tokens each, 2-deep.

#define NTOK 16
#define NW 8

__device__ __forceinline__ float sigmoid_f(float z) {
    return 1.0f / (1.0f + __expf(-z));
}

// sum over each aligned 16-lane row via DPP row_ror (VALU-only)
__device__ __forceinline__ float row16_sum(float x) {
    x += __int_as_float(__builtin_amdgcn_update_dpp(
        0, __float_as_int(x), 0x121, 0xf, 0xf, false)); // row_ror:1
    x += __int_as_float(__builtin_amdgcn_update_dpp(
        0, __float_as_int(x), 0x122, 0xf, 0xf, false)); // row_ror:2
    x += __int_as_float(__builtin_amdgcn_update_dpp(
        0, __float_as_int(x), 0x124, 0xf, 0xf, false)); // row_ror:4
    x += __int_as_float(__builtin_amdgcn_update_dpp(
        0, __float_as_int(x), 0x128, 0xf, 0xf, false)); // row_ror:8
    return x;
}

__global__ __launch_bounds__(512, 4)
void mhc_kernel(const float* __restrict__ h,
                const float* __restrict__ nw,
                const float* __restrict__ w,
                const float* __restrict__ alpha,
                const float* __restrict__ beta,
                float* __restrict__ out)
{
    const int tid  = threadIdx.x;
    const int lane = tid & 63;
    const int wv   = tid >> 6;     // wave id = k-eighth (0..7)
    const int ksl  = lane & 15;    // k-slice within eighth
    const int ng   = lane >> 4;    // n-group (6 n's each)

    __shared__ float Cpart[NW][NTOK][28];  // per-wave partials; [24] = r2 part
    __shared__ float Hpart[NTOK][28];      // reduced H + r2
    __shared__ float smalls[NTOK][26];     // Hpre, Hpost, P

    // ---- fold alpha*nw*w into 48 register weights ----
    // thread owns k = 128*wv + 64*e + 4*ksl + c (e in 0..1, c in 0..3)
    const int kbase = 128 * wv;
    const float a0 = alpha[0], a1 = alpha[1], a2 = alpha[2];
    float w2r[8][6];
    #pragma unroll
    for (int e = 0; e < 2; ++e) {
        #pragma unroll
        for (int c = 0; c < 4; ++c) {
            const int k = kbase + 64 * e + 4 * ksl + c;
            const float nwk = nw[k];
            #pragma unroll
            for (int j = 0; j < 6; ++j) {
                const int n = 6 * ng + j;
                const float as = (n < 4) ? a0 : ((n < 8) ? a1 : a2);
                w2r[4 * e + c][j] = as * nwk * w[k * 24 + n];
            }
        }
    }

    const long tok0 = (long)blockIdx.x * NTOK;
    const float* pA = h + tok0 * 1024 + kbase + 4 * ksl;

    // prefetch token 0: 2 coalesced float4 loads (256B segments)
    float4 xb0 = *(const float4*)(pA + 0);
    float4 xb1 = *(const float4*)(pA + 64);

    // =================== phase A: 16 tokens, no barriers ===================
    #pragma unroll 1
    for (int it = 0; it < NTOK; ++it) {
        float x[8];
        x[0]=xb0.x; x[1]=xb0.y; x[2]=xb0.z; x[3]=xb0.w;
        x[4]=xb1.x; x[5]=xb1.y; x[6]=xb1.z; x[7]=xb1.w;

        if (it + 1 < NTOK) {    // prefetch next token (coalesced)
            const float* p = pA + (it + 1) * 1024;
            xb0 = *(const float4*)(p + 0);
            xb1 = *(const float4*)(p + 64);
        }

        // keep w2r pinned (48 regs fit comfortably now -> identity op)
        #pragma unroll
        for (int e = 0; e < 8; ++e)
            #pragma unroll
            for (int j = 0; j < 6; ++j)
                asm volatile("" : "+v"(w2r[e][j]));

        float acc[6] = {0.f, 0.f, 0.f, 0.f, 0.f, 0.f};
        float r2 = 0.f;
        #pragma unroll
        for (int e = 0; e < 8; ++e) {
            const float xv = x[e];
            acc[0] = fmaf(xv, w2r[e][0], acc[0]);
            acc[1] = fmaf(xv, w2r[e][1], acc[1]);
            acc[2] = fmaf(xv, w2r[e][2], acc[2]);
            acc[3] = fmaf(xv, w2r[e][3], acc[3]);
            acc[4] = fmaf(xv, w2r[e][4], acc[4]);
            acc[5] = fmaf(xv, w2r[e][5], acc[5]);
            r2     = fmaf(xv, xv, r2);
        }

        // 16-lane DPP tree: every lane in a row gets the row sum
        acc[0] = row16_sum(acc[0]);
        acc[1] = row16_sum(acc[1]);
        acc[2] = row16_sum(acc[2]);
        acc[3] = row16_sum(acc[3]);
        acc[4] = row16_sum(acc[4]);
        acc[5] = row16_sum(acc[5]);
        r2     = row16_sum(r2);

        if (ksl == 0) {
            #pragma unroll
            for (int j = 0; j < 6; ++j)
                Cpart[wv][it][6 * ng + j] = acc[j];
            if (ng == 0) Cpart[wv][it][24] = r2;  // eighth-r2
        }
    }
    __syncthreads();

    // ---- deferred cross-wave reduce: Hpart[t][c] = sum_w Cpart[w][t][c] ----
    {
        const int j = tid;                 // 400 jobs < 512 threads
        if (j < NTOK * 25) {
            const int t = j / 25;
            const int c = j - 25 * t;
            float s = 0.f;
            #pragma unroll
            for (int ww = 0; ww < NW; ++ww) s += Cpart[ww][t][c];
            Hpart[t][c] = s;
        }
    }
    __syncthreads();

    // ---- scalar phase: lanes 0..15, one token each (R2-proven) ----
    if (tid < NTOK) {
        const int t = tid;
        float Hp[24];
        #pragma unroll
        for (int q = 0; q < 24; ++q) Hp[q] = Hpart[t][q];
        const float r2v = Hpart[t][24];
        const float r_ = 1.0f / (sqrtf(r2v) * 0.03125f + 1e-6f);

        float Hpre[4], Hpost[4], K[16];
        #pragma unroll
        for (int n = 0; n < 4; ++n)
            Hpre[n] = sigmoid_f(fmaf(r_, Hp[n], beta[n]));
        #pragma unroll
        for (int n = 0; n < 4; ++n)
            Hpost[n] = 2.0f * sigmoid_f(fmaf(r_, Hp[4 + n], beta[4 + n]));
        #pragma unroll
        for (int q = 0; q < 16; ++q)
            K[q] = __expf(fmaf(r_, Hp[8 + q], beta[8 + q]));

        float u0=1.f,u1=1.f,u2=1.f,u3=1.f;
        float v0=1.f,v1=1.f,v2=1.f,v3=1.f;
        for (int itr = 0; itr < 10; ++itr) {
            u0 = 1.0f/(K[0]*v0  + K[1]*v1  + K[2]*v2  + K[3]*v3  + 1e-8f);
            u1 = 1.0f/(K[4]*v0  + K[5]*v1  + K[6]*v2  + K[7]*v3  + 1e-8f);
            u2 = 1.0f/(K[8]*v0  + K[9]*v1  + K[10]*v2 + K[11]*v3 + 1e-8f);
            u3 = 1.0f/(K[12]*v0 + K[13]*v1 + K[14]*v2 + K[15]*v3 + 1e-8f);
            v0 = 1.0f/(K[0]*u0  + K[4]*u1  + K[8]*u2  + K[12]*u3 + 1e-8f);
            v1 = 1.0f/(K[1]*u0  + K[5]*u1  + K[9]*u2  + K[13]*u3 + 1e-8f);
            v2 = 1.0f/(K[2]*u0  + K[6]*u1  + K[10]*u2 + K[14]*u3 + 1e-8f);
            v3 = 1.0f/(K[3]*u0  + K[7]*u1  + K[11]*u2 + K[15]*u3 + 1e-8f);
        }
        smalls[t][0] = Hpre[0];  smalls[t][1] = Hpre[1];
        smalls[t][2] = Hpre[2];  smalls[t][3] = Hpre[3];
        smalls[t][4] = Hpost[0]; smalls[t][5] = Hpost[1];
        smalls[t][6] = Hpost[2]; smalls[t][7] = Hpost[3];
        smalls[t][8]  = u0*K[0]*v0;   smalls[t][9]  = u0*K[1]*v1;
        smalls[t][10] = u0*K[2]*v2;   smalls[t][11] = u0*K[3]*v3;
        smalls[t][12] = u1*K[4]*v0;   smalls[t][13] = u1*K[5]*v1;
        smalls[t][14] = u1*K[6]*v2;   smalls[t][15] = u1*K[7]*v3;
        smalls[t][16] = u2*K[8]*v0;   smalls[t][17] = u2*K[9]*v1;
        smalls[t][18] = u2*K[10]*v2;  smalls[t][19] = u2*K[11]*v3;
        smalls[t][20] = u3*K[12]*v0;  smalls[t][21] = u3*K[13]*v1;
        smalls[t][22] = u3*K[14]*v2;  smalls[t][23] = u3*K[15]*v3;
    }
    __syncthreads();

    // ---- phase C: 8 waves = (n = wv&3) x (token-half = wv>>2), 8 tok each --
    const int gg = wv & 3;           // output n
    const int th = wv >> 2;          // token half
    const int itb = th * 8;          // first token of this wave's half
    const float* p0 = h + (tok0 + itb) * 1024 + 4 * lane;
    float4 ca0, ca1, ca2, ca3, cb0, cb1, cb2, cb3;
    {
        ca0 = *(const float4*)(p0);       ca1 = *(const float4*)(p0 + 256);
        ca2 = *(const float4*)(p0 + 512); ca3 = *(const float4*)(p0 + 768);
        const float* q = p0 + 1024;
        cb0 = *(const float4*)(q);        cb1 = *(const float4*)(q + 256);
        cb2 = *(const float4*)(q + 512);  cb3 = *(const float4*)(q + 768);
    }
    for (int i = 0; i < 8; ++i) {
        const int it = itb + i;
        const long tok = tok0 + it;
        const float4 xm0 = ca0, xm1 = ca1, xm2 = ca2, xm3 = ca3;
        ca0 = cb0; ca1 = cb1; ca2 = cb2; ca3 = cb3;
        if (i + 2 < 8) {
            const float* p = p0 + (i + 2) * 1024;
            cb0 = *(const float4*)(p);       cb1 = *(const float4*)(p + 256);
            cb2 = *(const float4*)(p + 512); cb3 = *(const float4*)(p + 768);
        }
        const float hp0 = smalls[it][0], hp1 = smalls[it][1];
        const float hp2 = smalls[it][2], hp3 = smalls[it][3];
        const float hpost = smalls[it][4 + gg];
        const float P0 = smalls[it][8 + 4*gg + 0];
        const float P1 = smalls[it][8 + 4*gg + 1];
        const float P2 = smalls[it][8 + 4*gg + 2];
        const float P3 = smalls[it][8 + 4*gg + 3];

        float4 o;
        {
            const float hpre = hp0*xm0.x + hp1*xm1.x + hp2*xm2.x + hp3*xm3.x;
            o.x = fmaf(hpost, hpre, P0*xm0.x + P1*xm1.x + P2*xm2.x + P3*xm3.x);
        }
        {
            const float hpre = hp0*xm0.y + hp1*xm1.y + hp2*xm2.y + hp3*xm3.y;
            o.y = fmaf(hpost, hpre, P0*xm0.y + P1*xm1.y + P2*xm2.y + P3*xm3.y);
        }
        {
            const float hpre = hp0*xm0.z + hp1*xm1.z + hp2*xm2.z + hp3*xm3.z;
            o.z = fmaf(hpost, hpre, P0*xm0.z + P1*xm1.z + P2*xm2.z + P3*xm3.z);
        }
        {
            const float hpre = hp0*xm0.w + hp1*xm1.w + hp2*xm2.w + hp3*xm3.w;
            o.w = fmaf(hpost, hpre, P0*xm0.w + P1*xm1.w + P2*xm2.w + P3*xm3.w);
        }
        *(float4*)(out + tok * 1024 + gg * 256 + 4 * lane) = o;
    }
}

extern "C" void kernel_launch(void* const* d_in, const int* in_sizes, int n_in,
                              void* d_out, int out_size, void* d_ws, size_t ws_size,
                              hipStream_t stream) {
    const float* h     = (const float*)d_in[0];
    const float* nw    = (const float*)d_in[1];
    const float* w     = (const float*)d_in[2];
    const float* alpha = (const float*)d_in[3];
    const float* beta  = (const float*)d_in[4];
    float* out = (float*)d_out;

    mhc_kernel<<<2048, 512, 0, stream>>>(h, nw, w, alpha, beta, out);
}

// Round 11
// 107.438 us; speedup vs baseline: 1.0343x; 1.0343x over previous
//
#include <hip/hip_runtime.h>
#include <math.h>

// ManifoldHyperConnectionFuse on MI355X — R10: accumulator-resident phase A.
// R7-R9 post-mortem: per-element asm-volatile pins made w2r SCRATCH-resident
// (VGPR_Count 84/84/48 << need, every round) -> ~3.2GB/launch scratch-L2
// traffic. R10 inverts the loop nest: per-token ACCUMULATORS are the
// register-resident state (loop-carried sums -> allocator must keep them;
// standard GEMM pattern), weights are STREAMED from L2 once per block.
//
// NTOK=8, grid=4096, 256 thr (4 waves = 4 k-quarters).
// Thread (wv, ksl 0..15, ng 0..3): k in {256wv+64e+4ksl+c}, n in 6ng..+6.
// Phase A: e-loop (unroll 1): fold 24 weights (L2-hot), 8 unrolled tokens:
//   coalesced float4 x-load (each h elem read ONCE) + 24 FMA + r2 FMA.
// DPP row16 reduce once per block -> Cpart[4][8][28]. 1 barrier.
// 8-way... 4-wave reduce (200 jobs). 1 barrier. Scalar phase (lanes 0..7).
// 1 barrier. Phase C (R2-proven fp32, 2-deep pipeline).

#define NTOK 8

__device__ __forceinline__ float sigmoid_f(float z) {
    return 1.0f / (1.0f + __expf(-z));
}

// sum over each aligned 16-lane row via DPP row_ror (VALU-only)
__device__ __forceinline__ float row16_sum(float x) {
    x += __int_as_float(__builtin_amdgcn_update_dpp(
        0, __float_as_int(x), 0x121, 0xf, 0xf, false)); // row_ror:1
    x += __int_as_float(__builtin_amdgcn_update_dpp(
        0, __float_as_int(x), 0x122, 0xf, 0xf, false)); // row_ror:2
    x += __int_as_float(__builtin_amdgcn_update_dpp(
        0, __float_as_int(x), 0x124, 0xf, 0xf, false)); // row_ror:4
    x += __int_as_float(__builtin_amdgcn_update_dpp(
        0, __float_as_int(x), 0x128, 0xf, 0xf, false)); // row_ror:8
    return x;
}

__global__ __launch_bounds__(256, 3)
void mhc_kernel(const float* __restrict__ h,
                const float* __restrict__ nw,
                const float* __restrict__ w,
                const float* __restrict__ alpha,
                const float* __restrict__ beta,
                float* __restrict__ out)
{
    const int tid  = threadIdx.x;
    const int lane = tid & 63;
    const int wv   = tid >> 6;     // wave id = k-quarter
    const int ksl  = lane & 15;    // k-slice within quarter
    const int ng   = lane >> 4;    // n-group (6 n's each)

    __shared__ float Cpart[4][NTOK][28];  // per-wave partials; [24] = r2 part
    __shared__ float Hpart[NTOK][28];     // reduced H + r2
    __shared__ float smalls[NTOK][26];    // Hpre, Hpost, P

    const float a0 = alpha[0], a1 = alpha[1], a2 = alpha[2];
    float asel[6];
    #pragma unroll
    for (int j = 0; j < 6; ++j) {
        const int n = 6 * ng + j;
        asel[j] = (n < 4) ? a0 : ((n < 8) ? a1 : a2);
    }

    const long tok0 = (long)blockIdx.x * NTOK;

    // ---- phase A: accumulators resident, weights streamed ----
    float acc[NTOK][6];
    float r2a[NTOK];
    #pragma unroll
    for (int t = 0; t < NTOK; ++t) {
        r2a[t] = 0.f;
        #pragma unroll
        for (int j = 0; j < 6; ++j) acc[t][j] = 0.f;
    }

    #pragma unroll 1
    for (int e = 0; e < 4; ++e) {
        const int ke = 256 * wv + 64 * e + 4 * ksl;

        // fold this chunk's 4k x 6n weights (L2-hot; short-lived registers)
        float wcc[4][6];
        #pragma unroll
        for (int c = 0; c < 4; ++c) {
            const int k = ke + c;
            const float nwk = nw[k];
            #pragma unroll
            for (int j = 0; j < 6; ++j)
                wcc[c][j] = asel[j] * nwk * w[k * 24 + 6 * ng + j];
        }

        const float* pe = h + tok0 * 1024 + ke;
        #pragma unroll
        for (int t = 0; t < NTOK; ++t) {
            const float4 x4 = *(const float4*)(pe + t * 1024);  // coalesced
            #pragma unroll
            for (int j = 0; j < 6; ++j) {
                float s = acc[t][j];
                s = fmaf(x4.x, wcc[0][j], s);
                s = fmaf(x4.y, wcc[1][j], s);
                s = fmaf(x4.z, wcc[2][j], s);
                s = fmaf(x4.w, wcc[3][j], s);
                acc[t][j] = s;
            }
            float r = r2a[t];
            r = fmaf(x4.x, x4.x, r);
            r = fmaf(x4.y, x4.y, r);
            r = fmaf(x4.z, x4.z, r);
            r = fmaf(x4.w, x4.w, r);
            r2a[t] = r;
        }
    }

    // ---- DPP reduce (once per block) + Cpart store ----
    #pragma unroll
    for (int t = 0; t < NTOK; ++t) {
        #pragma unroll
        for (int j = 0; j < 6; ++j) acc[t][j] = row16_sum(acc[t][j]);
        r2a[t] = row16_sum(r2a[t]);
    }
    if (ksl == 0) {
        #pragma unroll
        for (int t = 0; t < NTOK; ++t) {
            #pragma unroll
            for (int j = 0; j < 6; ++j)
                Cpart[wv][t][6 * ng + j] = acc[t][j];
            if (ng == 0) Cpart[wv][t][24] = r2a[t];
        }
    }
    __syncthreads();

    // ---- cross-wave reduce: Hpart[t][c] = sum_w Cpart[w][t][c] ----
    if (tid < NTOK * 25) {
        const int t = tid / 25;
        const int c = tid - 25 * t;
        Hpart[t][c] = Cpart[0][t][c] + Cpart[1][t][c] +
                      Cpart[2][t][c] + Cpart[3][t][c];
    }
    __syncthreads();

    // ---- scalar phase: lanes 0..7, one token each (R2-proven) ----
    if (tid < NTOK) {
        const int t = tid;
        float Hp[24];
        #pragma unroll
        for (int q = 0; q < 24; ++q) Hp[q] = Hpart[t][q];
        const float r2v = Hpart[t][24];
        const float r_ = 1.0f / (sqrtf(r2v) * 0.03125f + 1e-6f);

        float Hpre[4], Hpost[4], K[16];
        #pragma unroll
        for (int n = 0; n < 4; ++n)
            Hpre[n] = sigmoid_f(fmaf(r_, Hp[n], beta[n]));
        #pragma unroll
        for (int n = 0; n < 4; ++n)
            Hpost[n] = 2.0f * sigmoid_f(fmaf(r_, Hp[4 + n], beta[4 + n]));
        #pragma unroll
        for (int q = 0; q < 16; ++q)
            K[q] = __expf(fmaf(r_, Hp[8 + q], beta[8 + q]));

        float u0=1.f,u1=1.f,u2=1.f,u3=1.f;
        float v0=1.f,v1=1.f,v2=1.f,v3=1.f;
        for (int itr = 0; itr < 10; ++itr) {
            u0 = 1.0f/(K[0]*v0  + K[1]*v1  + K[2]*v2  + K[3]*v3  + 1e-8f);
            u1 = 1.0f/(K[4]*v0  + K[5]*v1  + K[6]*v2  + K[7]*v3  + 1e-8f);
            u2 = 1.0f/(K[8]*v0  + K[9]*v1  + K[10]*v2 + K[11]*v3 + 1e-8f);
            u3 = 1.0f/(K[12]*v0 + K[13]*v1 + K[14]*v2 + K[15]*v3 + 1e-8f);
            v0 = 1.0f/(K[0]*u0  + K[4]*u1  + K[8]*u2  + K[12]*u3 + 1e-8f);
            v1 = 1.0f/(K[1]*u0  + K[5]*u1  + K[9]*u2  + K[13]*u3 + 1e-8f);
            v2 = 1.0f/(K[2]*u0  + K[6]*u1  + K[10]*u2 + K[14]*u3 + 1e-8f);
            v3 = 1.0f/(K[3]*u0  + K[7]*u1  + K[11]*u2 + K[15]*u3 + 1e-8f);
        }
        smalls[t][0] = Hpre[0];  smalls[t][1] = Hpre[1];
        smalls[t][2] = Hpre[2];  smalls[t][3] = Hpre[3];
        smalls[t][4] = Hpost[0]; smalls[t][5] = Hpost[1];
        smalls[t][6] = Hpost[2]; smalls[t][7] = Hpost[3];
        smalls[t][8]  = u0*K[0]*v0;   smalls[t][9]  = u0*K[1]*v1;
        smalls[t][10] = u0*K[2]*v2;   smalls[t][11] = u0*K[3]*v3;
        smalls[t][12] = u1*K[4]*v0;   smalls[t][13] = u1*K[5]*v1;
        smalls[t][14] = u1*K[6]*v2;   smalls[t][15] = u1*K[7]*v3;
        smalls[t][16] = u2*K[8]*v0;   smalls[t][17] = u2*K[9]*v1;
        smalls[t][18] = u2*K[10]*v2;  smalls[t][19] = u2*K[11]*v3;
        smalls[t][20] = u3*K[12]*v0;  smalls[t][21] = u3*K[13]*v1;
        smalls[t][22] = u3*K[14]*v2;  smalls[t][23] = u3*K[15]*v3;
    }
    __syncthreads();

    // ---- phase C: out = Hpost*h_pre + P@h (R2-proven, fp32) ----
    const int gg = wv;   // n = gg, d = 4*lane..+3
    const float* p0 = h + tok0 * 1024 + 4 * lane;
    float4 ca0, ca1, ca2, ca3, cb0, cb1, cb2, cb3;
    {
        ca0 = *(const float4*)(p0);       ca1 = *(const float4*)(p0 + 256);
        ca2 = *(const float4*)(p0 + 512); ca3 = *(const float4*)(p0 + 768);
        const float* q = p0 + 1024;
        cb0 = *(const float4*)(q);        cb1 = *(const float4*)(q + 256);
        cb2 = *(const float4*)(q + 512);  cb3 = *(const float4*)(q + 768);
    }
    for (int it = 0; it < NTOK; ++it) {
        const long tok = tok0 + it;
        const float4 xm0 = ca0, xm1 = ca1, xm2 = ca2, xm3 = ca3;
        ca0 = cb0; ca1 = cb1; ca2 = cb2; ca3 = cb3;
        if (it + 2 < NTOK) {
            const float* p = p0 + (it + 2) * 1024;
            cb0 = *(const float4*)(p);       cb1 = *(const float4*)(p + 256);
            cb2 = *(const float4*)(p + 512); cb3 = *(const float4*)(p + 768);
        }
        const float hp0 = smalls[it][0], hp1 = smalls[it][1];
        const float hp2 = smalls[it][2], hp3 = smalls[it][3];
        const float hpost = smalls[it][4 + gg];
        const float P0 = smalls[it][8 + 4*gg + 0];
        const float P1 = smalls[it][8 + 4*gg + 1];
        const float P2 = smalls[it][8 + 4*gg + 2];
        const float P3 = smalls[it][8 + 4*gg + 3];

        float4 o;
        {
            const float hpre = hp0*xm0.x + hp1*xm1.x + hp2*xm2.x + hp3*xm3.x;
            o.x = fmaf(hpost, hpre, P0*xm0.x + P1*xm1.x + P2*xm2.x + P3*xm3.x);
        }
        {
            const float hpre = hp0*xm0.y + hp1*xm1.y + hp2*xm2.y + hp3*xm3.y;
            o.y = fmaf(hpost, hpre, P0*xm0.y + P1*xm1.y + P2*xm2.y + P3*xm3.y);
        }
        {
            const float hpre = hp0*xm0.z + hp1*xm1.z + hp2*xm2.z + hp3*xm3.z;
            o.z = fmaf(hpost, hpre, P0*xm0.z + P1*xm1.z + P2*xm2.z + P3*xm3.z);
        }
        {
            const float hpre = hp0*xm0.w + hp1*xm1.w + hp2*xm2.w + hp3*xm3.w;
            o.w = fmaf(hpost, hpre, P0*xm0.w + P1*xm1.w + P2*xm2.w + P3*xm3.w);
        }
        *(float4*)(out + tok * 1024 + gg * 256 + 4 * lane) = o;
    }
}

extern "C" void kernel_launch(void* const* d_in, const int* in_sizes, int n_in,
                              void* d_out, int out_size, void* d_ws, size_t ws_size,
                              hipStream_t stream) {
    const float* h     = (const float*)d_in[0];
    const float* nw    = (const float*)d_in[1];
    const float* w     = (const float*)d_in[2];
    const float* alpha = (const float*)d_in[3];
    const float* beta  = (const float*)d_in[4];
    float* out = (float*)d_out;

    // 32768 tokens / 8 per block = 4096 blocks of 256 threads
    mhc_kernel<<<4096, 256, 0, stream>>>(h, nw, w, alpha, beta, out);
}

// Round 12
// 89.825 us; speedup vs baseline: 1.2371x; 1.1961x over previous
//
#include <hip/hip_runtime.h>
#include <math.h>

// ManifoldHyperConnectionFuse on MI355X — R11: LDS bf16 weights, wave-owns-tokens.
// R7-R10 proven: (1) per-thread weight arrays >=48 floats always spill,
// (2) scattered w[k*24+n] fold loads cost ~16-32 cache lines per inst,
// (3) kernel is latency-bound (nothing saturated). Fix all three:
//   - fold alpha*nw*w ONCE per block into LDS as bf16, transposed wT[24][1040]
//     (49.9KB), built from coalesced float4 reads of w.
//   - wave owns 4 TOKENS (lane ksl covers k = 64e+4ksl+c over e=0..15):
//     16-lane DPP reduce yields FINAL H -> no Cpart, no cross-wave pass.
//   - per-thread live set ~80 regs (acc[4][6]+r2[4]+wcc[4][6]) - no spill.
// LDS 53.4KB -> 3 blocks/CU (12 waves). Grid 2048 x 256thr, NTOK=16.
// Scalar phase + phase C unchanged (R2-proven).

#define NTOK 16

__device__ __forceinline__ unsigned short f2bf(float f) {
    unsigned int u = __float_as_uint(f);
    return (unsigned short)((u + 0x7FFFu + ((u >> 16) & 1u)) >> 16);
}
__device__ __forceinline__ float sigmoid_f(float z) {
    return 1.0f / (1.0f + __expf(-z));
}

// sum over each aligned 16-lane row via DPP row_ror (VALU-only)
__device__ __forceinline__ float row16_sum(float x) {
    x += __int_as_float(__builtin_amdgcn_update_dpp(
        0, __float_as_int(x), 0x121, 0xf, 0xf, false)); // row_ror:1
    x += __int_as_float(__builtin_amdgcn_update_dpp(
        0, __float_as_int(x), 0x122, 0xf, 0xf, false)); // row_ror:2
    x += __int_as_float(__builtin_amdgcn_update_dpp(
        0, __float_as_int(x), 0x124, 0xf, 0xf, false)); // row_ror:4
    x += __int_as_float(__builtin_amdgcn_update_dpp(
        0, __float_as_int(x), 0x128, 0xf, 0xf, false)); // row_ror:8
    return x;
}

__global__ __launch_bounds__(256, 3)
void mhc_kernel(const float* __restrict__ h,
                const float* __restrict__ nw,
                const float* __restrict__ w,
                const float* __restrict__ alpha,
                const float* __restrict__ beta,
                float* __restrict__ out)
{
    const int tid  = threadIdx.x;
    const int lane = tid & 63;
    const int wv   = tid >> 6;     // wave id: owns tokens [4wv, 4wv+4)
    const int ksl  = lane & 15;    // k-slice lane
    const int ng   = lane >> 4;    // n-group (6 n's each)

    __shared__ unsigned short wT[24][1040];  // folded bf16 weights, transposed
    __shared__ float Hpart[NTOK][28];        // [0:24) H, [24] r2
    __shared__ float smalls[NTOK][26];       // Hpre, Hpost, P

    const float a0 = alpha[0], a1 = alpha[1], a2 = alpha[2];

    // ---- build stage: fold weights into LDS (coalesced w reads) ----
    // thread covers flat indices {4*tid + 1024*i + c}, i<24, c<4 (96 elems)
    #pragma unroll 4
    for (int i = 0; i < 24; ++i) {
        const int flat = 4 * tid + 1024 * i;
        const float4 w4 = *(const float4*)(w + flat);
        const float vals[4] = {w4.x, w4.y, w4.z, w4.w};
        #pragma unroll
        for (int c = 0; c < 4; ++c) {
            const int f = flat + c;
            const int k = f / 24;           // magic-mul div
            const int n = f - 24 * k;
            const float as = (n < 4) ? a0 : ((n < 8) ? a1 : a2);
            wT[n][k] = f2bf(as * nw[k] * vals[c]);
        }
    }
    __syncthreads();

    const long tok0 = (long)blockIdx.x * NTOK;
    const int t0 = 4 * wv;                  // this wave's first token
    const float* ph = h + (tok0 + t0) * 1024 + 4 * ksl;

    // ---- phase A: 4 tokens/wave, full k-range per wave ----
    float acc[4][6], r2[4];
    #pragma unroll
    for (int t = 0; t < 4; ++t) {
        r2[t] = 0.f;
        #pragma unroll
        for (int j = 0; j < 6; ++j) acc[t][j] = 0.f;
    }

    #pragma unroll 1
    for (int e = 0; e < 16; ++e) {
        const int kw = 64 * e + 4 * ksl;    // this lane's 4 k's
        float wcc[4][6];
        #pragma unroll
        for (int j = 0; j < 6; ++j) {
            const uint2 u = *(const uint2*)&wT[6 * ng + j][kw];
            wcc[0][j] = __uint_as_float(u.x << 16);
            wcc[1][j] = __uint_as_float(u.x & 0xffff0000u);
            wcc[2][j] = __uint_as_float(u.y << 16);
            wcc[3][j] = __uint_as_float(u.y & 0xffff0000u);
        }
        #pragma unroll
        for (int t = 0; t < 4; ++t) {
            const float4 x4 = *(const float4*)(ph + t * 1024 + 64 * e);
            #pragma unroll
            for (int j = 0; j < 6; ++j) {
                float s = acc[t][j];
                s = fmaf(x4.x, wcc[0][j], s);
                s = fmaf(x4.y, wcc[1][j], s);
                s = fmaf(x4.z, wcc[2][j], s);
                s = fmaf(x4.w, wcc[3][j], s);
                acc[t][j] = s;
            }
            float r = r2[t];
            r = fmaf(x4.x, x4.x, r);
            r = fmaf(x4.y, x4.y, r);
            r = fmaf(x4.z, x4.z, r);
            r = fmaf(x4.w, x4.w, r);
            r2[t] = r;
        }
    }

    // ---- DPP reduce over ksl -> FINAL H for this wave's 4 tokens ----
    #pragma unroll
    for (int t = 0; t < 4; ++t) {
        #pragma unroll
        for (int j = 0; j < 6; ++j) acc[t][j] = row16_sum(acc[t][j]);
        r2[t] = row16_sum(r2[t]);
    }
    if (ksl == 0) {
        #pragma unroll
        for (int t = 0; t < 4; ++t) {
            #pragma unroll
            for (int j = 0; j < 6; ++j)
                Hpart[t0 + t][6 * ng + j] = acc[t][j];
            if (ng == 0) Hpart[t0 + t][24] = r2[t];
        }
    }
    __syncthreads();

    // ---- scalar phase: lanes 0..15, one token each (R2-proven) ----
    if (tid < NTOK) {
        const int t = tid;
        float Hp[24];
        #pragma unroll
        for (int q = 0; q < 24; ++q) Hp[q] = Hpart[t][q];
        const float r2v = Hpart[t][24];
        const float r_ = 1.0f / (sqrtf(r2v) * 0.03125f + 1e-6f);

        float Hpre[4], Hpost[4], K[16];
        #pragma unroll
        for (int n = 0; n < 4; ++n)
            Hpre[n] = sigmoid_f(fmaf(r_, Hp[n], beta[n]));
        #pragma unroll
        for (int n = 0; n < 4; ++n)
            Hpost[n] = 2.0f * sigmoid_f(fmaf(r_, Hp[4 + n], beta[4 + n]));
        #pragma unroll
        for (int q = 0; q < 16; ++q)
            K[q] = __expf(fmaf(r_, Hp[8 + q], beta[8 + q]));

        float u0=1.f,u1=1.f,u2=1.f,u3=1.f;
        float v0=1.f,v1=1.f,v2=1.f,v3=1.f;
        for (int itr = 0; itr < 10; ++itr) {
            u0 = 1.0f/(K[0]*v0  + K[1]*v1  + K[2]*v2  + K[3]*v3  + 1e-8f);
            u1 = 1.0f/(K[4]*v0  + K[5]*v1  + K[6]*v2  + K[7]*v3  + 1e-8f);
            u2 = 1.0f/(K[8]*v0  + K[9]*v1  + K[10]*v2 + K[11]*v3 + 1e-8f);
            u3 = 1.0f/(K[12]*v0 + K[13]*v1 + K[14]*v2 + K[15]*v3 + 1e-8f);
            v0 = 1.0f/(K[0]*u0  + K[4]*u1  + K[8]*u2  + K[12]*u3 + 1e-8f);
            v1 = 1.0f/(K[1]*u0  + K[5]*u1  + K[9]*u2  + K[13]*u3 + 1e-8f);
            v2 = 1.0f/(K[2]*u0  + K[6]*u1  + K[10]*u2 + K[14]*u3 + 1e-8f);
            v3 = 1.0f/(K[3]*u0  + K[7]*u1  + K[11]*u2 + K[15]*u3 + 1e-8f);
        }
        smalls[t][0] = Hpre[0];  smalls[t][1] = Hpre[1];
        smalls[t][2] = Hpre[2];  smalls[t][3] = Hpre[3];
        smalls[t][4] = Hpost[0]; smalls[t][5] = Hpost[1];
        smalls[t][6] = Hpost[2]; smalls[t][7] = Hpost[3];
        smalls[t][8]  = u0*K[0]*v0;   smalls[t][9]  = u0*K[1]*v1;
        smalls[t][10] = u0*K[2]*v2;   smalls[t][11] = u0*K[3]*v3;
        smalls[t][12] = u1*K[4]*v0;   smalls[t][13] = u1*K[5]*v1;
        smalls[t][14] = u1*K[6]*v2;   smalls[t][15] = u1*K[7]*v3;
        smalls[t][16] = u2*K[8]*v0;   smalls[t][17] = u2*K[9]*v1;
        smalls[t][18] = u2*K[10]*v2;  smalls[t][19] = u2*K[11]*v3;
        smalls[t][20] = u3*K[12]*v0;  smalls[t][21] = u3*K[13]*v1;
        smalls[t][22] = u3*K[14]*v2;  smalls[t][23] = u3*K[15]*v3;
    }
    __syncthreads();

    // ---- phase C: out = Hpost*h_pre + P@h (R2-proven, fp32) ----
    const int gg = wv;   // n = gg, d = 4*lane..+3
    const float* p0 = h + tok0 * 1024 + 4 * lane;
    float4 ca0, ca1, ca2, ca3, cb0, cb1, cb2, cb3;
    {
        ca0 = *(const float4*)(p0);       ca1 = *(const float4*)(p0 + 256);
        ca2 = *(const float4*)(p0 + 512); ca3 = *(const float4*)(p0 + 768);
        const float* q = p0 + 1024;
        cb0 = *(const float4*)(q);        cb1 = *(const float4*)(q + 256);
        cb2 = *(const float4*)(q + 512);  cb3 = *(const float4*)(q + 768);
    }
    for (int it = 0; it < NTOK; ++it) {
        const long tok = tok0 + it;
        const float4 xm0 = ca0, xm1 = ca1, xm2 = ca2, xm3 = ca3;
        ca0 = cb0; ca1 = cb1; ca2 = cb2; ca3 = cb3;
        if (it + 2 < NTOK) {
            const float* p = p0 + (it + 2) * 1024;
            cb0 = *(const float4*)(p);       cb1 = *(const float4*)(p + 256);
            cb2 = *(const float4*)(p + 512); cb3 = *(const float4*)(p + 768);
        }
        const float hp0 = smalls[it][0], hp1 = smalls[it][1];
        const float hp2 = smalls[it][2], hp3 = smalls[it][3];
        const float hpost = smalls[it][4 + gg];
        const float P0 = smalls[it][8 + 4*gg + 0];
        const float P1 = smalls[it][8 + 4*gg + 1];
        const float P2 = smalls[it][8 + 4*gg + 2];
        const float P3 = smalls[it][8 + 4*gg + 3];

        float4 o;
        {
            const float hpre = hp0*xm0.x + hp1*xm1.x + hp2*xm2.x + hp3*xm3.x;
            o.x = fmaf(hpost, hpre, P0*xm0.x + P1*xm1.x + P2*xm2.x + P3*xm3.x);
        }
        {
            const float hpre = hp0*xm0.y + hp1*xm1.y + hp2*xm2.y + hp3*xm3.y;
            o.y = fmaf(hpost, hpre, P0*xm0.y + P1*xm1.y + P2*xm2.y + P3*xm3.y);
        }
        {
            const float hpre = hp0*xm0.z + hp1*xm1.z + hp2*xm2.z + hp3*xm3.z;
            o.z = fmaf(hpost, hpre, P0*xm0.z + P1*xm1.z + P2*xm2.z + P3*xm3.z);
        }
        {
            const float hpre = hp0*xm0.w + hp1*xm1.w + hp2*xm2.w + hp3*xm3.w;
            o.w = fmaf(hpost, hpre, P0*xm0.w + P1*xm1.w + P2*xm2.w + P3*xm3.w);
        }
        *(float4*)(out + tok * 1024 + gg * 256 + 4 * lane) = o;
    }
}

extern "C" void kernel_launch(void* const* d_in, const int* in_sizes, int n_in,
                              void* d_out, int out_size, void* d_ws, size_t ws_size,
                              hipStream_t stream) {
    const float* h     = (const float*)d_in[0];
    const float* nw    = (const float*)d_in[1];
    const float* w     = (const float*)d_in[2];
    const float* alpha = (const float*)d_in[3];
    const float* beta  = (const float*)d_in[4];
    float* out = (float*)d_out;

    mhc_kernel<<<2048, 256, 0, stream>>>(h, nw, w, alpha, beta, out);
}

// Round 13
// 87.299 us; speedup vs baseline: 1.2729x; 1.0289x over previous
//
#include <hip/hip_runtime.h>
#include <math.h>

// ManifoldHyperConnectionFuse on MI355X — R12: d_ws weight table, no LDS table.
// R11 post-mortem: 50KB LDS wT capped occupancy at 2 blocks/CU (28%) and its
// 4-row-parallel reads were a structural 4-way bank conflict (9.4M cycles).
// R12: fold alpha*nw*w ONCE into d_ws as bf16 wt[24][1024] via a prep kernel
// (48KB, L2-resident chip-wide). Main kernel:
//   - no LDS weight table (LDS = 3.5KB) -> 4 blocks/CU at VGPR<=128
//   - weights read per-e from global (coalesced 128B segments, L2-hot)
//   - x-loads AND w-loads double-buffered across the e-loop (latency hidden)
//   - wave owns 4 tokens; 16-lane DPP reduce -> final H (no cross-wave pass)
// Scalar phase + phase C unchanged (R2-proven).

#define NTOK 16

__device__ __forceinline__ unsigned short f2bf(float f) {
    unsigned int u = __float_as_uint(f);
    return (unsigned short)((u + 0x7FFFu + ((u >> 16) & 1u)) >> 16);
}
__device__ __forceinline__ float bflo(unsigned int u) {
    return __uint_as_float(u << 16);
}
__device__ __forceinline__ float bfhi(unsigned int u) {
    return __uint_as_float(u & 0xffff0000u);
}
__device__ __forceinline__ float sigmoid_f(float z) {
    return 1.0f / (1.0f + __expf(-z));
}

// sum over each aligned 16-lane row via DPP row_ror (VALU-only)
__device__ __forceinline__ float row16_sum(float x) {
    x += __int_as_float(__builtin_amdgcn_update_dpp(
        0, __float_as_int(x), 0x121, 0xf, 0xf, false)); // row_ror:1
    x += __int_as_float(__builtin_amdgcn_update_dpp(
        0, __float_as_int(x), 0x122, 0xf, 0xf, false)); // row_ror:2
    x += __int_as_float(__builtin_amdgcn_update_dpp(
        0, __float_as_int(x), 0x124, 0xf, 0xf, false)); // row_ror:4
    x += __int_as_float(__builtin_amdgcn_update_dpp(
        0, __float_as_int(x), 0x128, 0xf, 0xf, false)); // row_ror:8
    return x;
}

// ---- prep: fold alpha*nw*w -> bf16 wt[24][1024] (n-major) in d_ws ----
__global__ __launch_bounds__(256)
void prep_kernel(const float* __restrict__ nw,
                 const float* __restrict__ w,
                 const float* __restrict__ alpha,
                 unsigned short* __restrict__ wt)
{
    const int tid = blockIdx.x * 256 + threadIdx.x;   // 6144 threads
    const int flat = 4 * tid;                          // w is [k][n], flat=k*24+n
    const float4 w4 = *(const float4*)(w + flat);
    const float a0 = alpha[0], a1 = alpha[1], a2 = alpha[2];
    const float vals[4] = {w4.x, w4.y, w4.z, w4.w};
    #pragma unroll
    for (int c = 0; c < 4; ++c) {
        const int f = flat + c;
        const int k = f / 24;
        const int n = f - 24 * k;
        const float as = (n < 4) ? a0 : ((n < 8) ? a1 : a2);
        wt[n * 1024 + k] = f2bf(as * nw[k] * vals[c]);
    }
}

__global__ __launch_bounds__(256, 4)
void mhc_kernel(const float* __restrict__ h,
                const unsigned short* __restrict__ wt,
                const float* __restrict__ beta,
                float* __restrict__ out)
{
    const int tid  = threadIdx.x;
    const int lane = tid & 63;
    const int wv   = tid >> 6;     // wave id: owns tokens [4wv, 4wv+4)
    const int ksl  = lane & 15;    // k-slice lane
    const int ng   = lane >> 4;    // n-group (6 n's each)

    __shared__ float Hpart[NTOK][28];   // [0:24) H, [24] r2
    __shared__ float smalls[NTOK][26];  // Hpre, Hpost, P

    const long tok0 = (long)blockIdx.x * NTOK;
    const int t0 = 4 * wv;
    const float* ph = h + (tok0 + t0) * 1024 + 4 * ksl;
    const unsigned short* pw = wt + (6 * ng) * 1024 + 4 * ksl;

    // ---- phase A: acc-resident, x & w double-buffered across e ----
    float acc[4][6], r2[4];
    #pragma unroll
    for (int t = 0; t < 4; ++t) {
        r2[t] = 0.f;
        #pragma unroll
        for (int j = 0; j < 6; ++j) acc[t][j] = 0.f;
    }

    float4 xa0, xa1, xa2, xa3;
    uint2  wa[6];
    xa0 = *(const float4*)(ph);
    xa1 = *(const float4*)(ph + 1024);
    xa2 = *(const float4*)(ph + 2048);
    xa3 = *(const float4*)(ph + 3072);
    #pragma unroll
    for (int j = 0; j < 6; ++j)
        wa[j] = *(const uint2*)(pw + j * 1024);

    #pragma unroll 1
    for (int e = 0; e < 16; ++e) {
        float4 xb0, xb1, xb2, xb3;
        uint2  wb[6];
        if (e + 1 < 16) {                 // issue e+1 loads before e compute
            const float* p = ph + (e + 1) * 64;
            xb0 = *(const float4*)(p);
            xb1 = *(const float4*)(p + 1024);
            xb2 = *(const float4*)(p + 2048);
            xb3 = *(const float4*)(p + 3072);
            const unsigned short* q = pw + (e + 1) * 64;
            #pragma unroll
            for (int j = 0; j < 6; ++j)
                wb[j] = *(const uint2*)(q + j * 1024);
        }

        #pragma unroll
        for (int j = 0; j < 6; ++j) {
            const float w0 = bflo(wa[j].x), w1 = bfhi(wa[j].x);
            const float w2 = bflo(wa[j].y), w3 = bfhi(wa[j].y);
            acc[0][j] = fmaf(xa0.w, w3, fmaf(xa0.z, w2,
                        fmaf(xa0.y, w1, fmaf(xa0.x, w0, acc[0][j]))));
            acc[1][j] = fmaf(xa1.w, w3, fmaf(xa1.z, w2,
                        fmaf(xa1.y, w1, fmaf(xa1.x, w0, acc[1][j]))));
            acc[2][j] = fmaf(xa2.w, w3, fmaf(xa2.z, w2,
                        fmaf(xa2.y, w1, fmaf(xa2.x, w0, acc[2][j]))));
            acc[3][j] = fmaf(xa3.w, w3, fmaf(xa3.z, w2,
                        fmaf(xa3.y, w1, fmaf(xa3.x, w0, acc[3][j]))));
        }
        r2[0] = fmaf(xa0.w, xa0.w, fmaf(xa0.z, xa0.z,
                fmaf(xa0.y, xa0.y, fmaf(xa0.x, xa0.x, r2[0]))));
        r2[1] = fmaf(xa1.w, xa1.w, fmaf(xa1.z, xa1.z,
                fmaf(xa1.y, xa1.y, fmaf(xa1.x, xa1.x, r2[1]))));
        r2[2] = fmaf(xa2.w, xa2.w, fmaf(xa2.z, xa2.z,
                fmaf(xa2.y, xa2.y, fmaf(xa2.x, xa2.x, r2[2]))));
        r2[3] = fmaf(xa3.w, xa3.w, fmaf(xa3.z, xa3.z,
                fmaf(xa3.y, xa3.y, fmaf(xa3.x, xa3.x, r2[3]))));

        xa0 = xb0; xa1 = xb1; xa2 = xb2; xa3 = xb3;
        #pragma unroll
        for (int j = 0; j < 6; ++j) wa[j] = wb[j];
    }

    // ---- DPP reduce over ksl -> FINAL H for this wave's 4 tokens ----
    #pragma unroll
    for (int t = 0; t < 4; ++t) {
        #pragma unroll
        for (int j = 0; j < 6; ++j) acc[t][j] = row16_sum(acc[t][j]);
        r2[t] = row16_sum(r2[t]);
    }
    if (ksl == 0) {
        #pragma unroll
        for (int t = 0; t < 4; ++t) {
            #pragma unroll
            for (int j = 0; j < 6; ++j)
                Hpart[t0 + t][6 * ng + j] = acc[t][j];
            if (ng == 0) Hpart[t0 + t][24] = r2[t];
        }
    }
    __syncthreads();

    // ---- scalar phase: lanes 0..15, one token each (R2-proven) ----
    if (tid < NTOK) {
        const int t = tid;
        float Hp[24];
        #pragma unroll
        for (int q = 0; q < 24; ++q) Hp[q] = Hpart[t][q];
        const float r2v = Hpart[t][24];
        const float r_ = 1.0f / (sqrtf(r2v) * 0.03125f + 1e-6f);

        float Hpre[4], Hpost[4], K[16];
        #pragma unroll
        for (int n = 0; n < 4; ++n)
            Hpre[n] = sigmoid_f(fmaf(r_, Hp[n], beta[n]));
        #pragma unroll
        for (int n = 0; n < 4; ++n)
            Hpost[n] = 2.0f * sigmoid_f(fmaf(r_, Hp[4 + n], beta[4 + n]));
        #pragma unroll
        for (int q = 0; q < 16; ++q)
            K[q] = __expf(fmaf(r_, Hp[8 + q], beta[8 + q]));

        float u0=1.f,u1=1.f,u2=1.f,u3=1.f;
        float v0=1.f,v1=1.f,v2=1.f,v3=1.f;
        for (int itr = 0; itr < 10; ++itr) {
            u0 = 1.0f/(K[0]*v0  + K[1]*v1  + K[2]*v2  + K[3]*v3  + 1e-8f);
            u1 = 1.0f/(K[4]*v0  + K[5]*v1  + K[6]*v2  + K[7]*v3  + 1e-8f);
            u2 = 1.0f/(K[8]*v0  + K[9]*v1  + K[10]*v2 + K[11]*v3 + 1e-8f);
            u3 = 1.0f/(K[12]*v0 + K[13]*v1 + K[14]*v2 + K[15]*v3 + 1e-8f);
            v0 = 1.0f/(K[0]*u0  + K[4]*u1  + K[8]*u2  + K[12]*u3 + 1e-8f);
            v1 = 1.0f/(K[1]*u0  + K[5]*u1  + K[9]*u2  + K[13]*u3 + 1e-8f);
            v2 = 1.0f/(K[2]*u0  + K[6]*u1  + K[10]*u2 + K[14]*u3 + 1e-8f);
            v3 = 1.0f/(K[3]*u0  + K[7]*u1  + K[11]*u2 + K[15]*u3 + 1e-8f);
        }
        smalls[t][0] = Hpre[0];  smalls[t][1] = Hpre[1];
        smalls[t][2] = Hpre[2];  smalls[t][3] = Hpre[3];
        smalls[t][4] = Hpost[0]; smalls[t][5] = Hpost[1];
        smalls[t][6] = Hpost[2]; smalls[t][7] = Hpost[3];
        smalls[t][8]  = u0*K[0]*v0;   smalls[t][9]  = u0*K[1]*v1;
        smalls[t][10] = u0*K[2]*v2;   smalls[t][11] = u0*K[3]*v3;
        smalls[t][12] = u1*K[4]*v0;   smalls[t][13] = u1*K[5]*v1;
        smalls[t][14] = u1*K[6]*v2;   smalls[t][15] = u1*K[7]*v3;
        smalls[t][16] = u2*K[8]*v0;   smalls[t][17] = u2*K[9]*v1;
        smalls[t][18] = u2*K[10]*v2;  smalls[t][19] = u2*K[11]*v3;
        smalls[t][20] = u3*K[12]*v0;  smalls[t][21] = u3*K[13]*v1;
        smalls[t][22] = u3*K[14]*v2;  smalls[t][23] = u3*K[15]*v3;
    }
    __syncthreads();

    // ---- phase C: out = Hpost*h_pre + P@h (R2-proven, fp32) ----
    const int gg = wv;   // n = gg, d = 4*lane..+3
    const float* p0 = h + tok0 * 1024 + 4 * lane;
    float4 ca0, ca1, ca2, ca3, cb0, cb1, cb2, cb3;
    {
        ca0 = *(const float4*)(p0);       ca1 = *(const float4*)(p0 + 256);
        ca2 = *(const float4*)(p0 + 512); ca3 = *(const float4*)(p0 + 768);
        const float* q = p0 + 1024;
        cb0 = *(const float4*)(q);        cb1 = *(const float4*)(q + 256);
        cb2 = *(const float4*)(q + 512);  cb3 = *(const float4*)(q + 768);
    }
    for (int it = 0; it < NTOK; ++it) {
        const long tok = tok0 + it;
        const float4 xm0 = ca0, xm1 = ca1, xm2 = ca2, xm3 = ca3;
        ca0 = cb0; ca1 = cb1; ca2 = cb2; ca3 = cb3;
        if (it + 2 < NTOK) {
            const float* p = p0 + (it + 2) * 1024;
            cb0 = *(const float4*)(p);       cb1 = *(const float4*)(p + 256);
            cb2 = *(const float4*)(p + 512); cb3 = *(const float4*)(p + 768);
        }
        const float hp0 = smalls[it][0], hp1 = smalls[it][1];
        const float hp2 = smalls[it][2], hp3 = smalls[it][3];
        const float hpost = smalls[it][4 + gg];
        const float P0 = smalls[it][8 + 4*gg + 0];
        const float P1 = smalls[it][8 + 4*gg + 1];
        const float P2 = smalls[it][8 + 4*gg + 2];
        const float P3 = smalls[it][8 + 4*gg + 3];

        float4 o;
        {
            const float hpre = hp0*xm0.x + hp1*xm1.x + hp2*xm2.x + hp3*xm3.x;
            o.x = fmaf(hpost, hpre, P0*xm0.x + P1*xm1.x + P2*xm2.x + P3*xm3.x);
        }
        {
            const float hpre = hp0*xm0.y + hp1*xm1.y + hp2*xm2.y + hp3*xm3.y;
            o.y = fmaf(hpost, hpre, P0*xm0.y + P1*xm1.y + P2*xm2.y + P3*xm3.y);
        }
        {
            const float hpre = hp0*xm0.z + hp1*xm1.z + hp2*xm2.z + hp3*xm3.z;
            o.z = fmaf(hpost, hpre, P0*xm0.z + P1*xm1.z + P2*xm2.z + P3*xm3.z);
        }
        {
            const float hpre = hp0*xm0.w + hp1*xm1.w + hp2*xm2.w + hp3*xm3.w;
            o.w = fmaf(hpost, hpre, P0*xm0.w + P1*xm1.w + P2*xm2.w + P3*xm3.w);
        }
        *(float4*)(out + tok * 1024 + gg * 256 + 4 * lane) = o;
    }
}

extern "C" void kernel_launch(void* const* d_in, const int* in_sizes, int n_in,
                              void* d_out, int out_size, void* d_ws, size_t ws_size,
                              hipStream_t stream) {
    const float* h     = (const float*)d_in[0];
    const float* nw    = (const float*)d_in[1];
    const float* w     = (const float*)d_in[2];
    const float* alpha = (const float*)d_in[3];
    const float* beta  = (const float*)d_in[4];
    float* out = (float*)d_out;
    unsigned short* wt = (unsigned short*)d_ws;   // 24*1024*2B = 48KB

    prep_kernel<<<24, 256, 0, stream>>>(nw, w, alpha, wt);
    mhc_kernel<<<2048, 256, 0, stream>>>(h, wt, beta, out);
}